// Round 5
// baseline (324.685 us; speedup 1.0000x reference)
//
// R5: R2 attn wave body at 16 q/wave, 4096 x 1-wave (64-thr) blocks = 4 waves/SIMD.
//     Grid math: per (b,h) 2048/16 = 128 waves; q0 = qw*16 (R4's bug was qw*32 with 4096 blocks).
//     No setprio. Compiler memory barrier between P LDS write (bf16x4) and read (bf16x8).
//     GEMMs/cvt bit-identical to R2 (known good).
#include <hip/hip_runtime.h>
#include <cstdint>
#include <cmath>

typedef __attribute__((ext_vector_type(8))) __bf16 bf16x8;
typedef __attribute__((ext_vector_type(4))) __bf16 bf16x4;
typedef __attribute__((ext_vector_type(4))) float f32x4;

static constexpr float SM_C = 0.125f * 1.44269504088896340736f; // 1/sqrt(64) * log2(e)

__device__ __forceinline__ f32x4 mfma16(bf16x8 a, bf16x8 b, f32x4 c) {
  return __builtin_amdgcn_mfma_f32_16x16x32_bf16(a, b, c, 0, 0, 0);
}

typedef __attribute__((address_space(1))) const void GVoid;
typedef __attribute__((address_space(3))) void LVoid;

__device__ __forceinline__ void load_lds16(const __bf16* g, __bf16* lds) {
  __builtin_amdgcn_global_load_lds((GVoid*)g, (LVoid*)lds, 16, 0, 0);
}

// ---------------- fp32 -> bf16 conversion (7 tensors in one launch) ----------------
struct CvtArgs {
  const float* src[7];
  __bf16* dst[7];
  int n8[7];
};

__global__ __launch_bounds__(256) void cvt_kernel(CvtArgs args) {
  const int t = blockIdx.y;
  const float* s = args.src[t];
  __bf16* d = args.dst[t];
  const int n8 = args.n8[t];
  for (int i = blockIdx.x * 256 + threadIdx.x; i < n8; i += gridDim.x * 256) {
    float4 f0 = reinterpret_cast<const float4*>(s)[2 * i];
    float4 f1 = reinterpret_cast<const float4*>(s)[2 * i + 1];
    bf16x8 o;
    o[0] = (__bf16)f0.x; o[1] = (__bf16)f0.y; o[2] = (__bf16)f0.z; o[3] = (__bf16)f0.w;
    o[4] = (__bf16)f1.x; o[5] = (__bf16)f1.y; o[6] = (__bf16)f1.z; o[7] = (__bf16)f1.w;
    reinterpret_cast<bf16x8*>(d)[i] = o;
  }
}

// ---------------- GEMM core (m97 config): 128x128 tile, BK=64, global_load_lds w16 ----------------
__device__ __forceinline__ void gemm_tile_128(
    const __bf16* __restrict__ A, const __bf16* __restrict__ W,
    int m0, int n0, __bf16* A_lds, __bf16* B_lds, f32x4 acc[4][4])
{
  const int tid = threadIdx.x;
  const int l = tid & 63, l15 = l & 15, l4 = l >> 4;
  const int w = tid >> 6;
  const int wr = (w >> 1) * 64, wc = (w & 1) * 64;

  #pragma unroll 1
  for (int kt = 0; kt < 1024; kt += 64) {
    __syncthreads();  // previous compute done before restaging
    #pragma unroll
    for (int c = 0; c < 4; ++c) {
      const int u = c * 256 + tid;          // 0..1023 16B units
      const int row = u >> 3, ch = (u & 7) * 8;
      load_lds16(A + (size_t)(m0 + row) * 1024 + kt + ch, A_lds + u * 8);
      load_lds16(W + (size_t)(n0 + row) * 1024 + kt + ch, B_lds + u * 8);
    }
    __syncthreads();  // drains vmcnt: LDS staged
    #pragma unroll
    for (int ks = 0; ks < 2; ++ks) {
      bf16x8 af[4], bw[4];
      #pragma unroll
      for (int i = 0; i < 4; ++i) {
        af[i] = *(const bf16x8*)(A_lds + (size_t)(wr + i * 16 + l15) * 64 + ks * 32 + l4 * 8);
        bw[i] = *(const bf16x8*)(B_lds + (size_t)(wc + i * 16 + l15) * 64 + ks * 32 + l4 * 8);
      }
      #pragma unroll
      for (int i = 0; i < 4; ++i)
        #pragma unroll
        for (int j = 0; j < 4; ++j)
          acc[i][j] = mfma16(af[i], bw[j], acc[i][j]);
    }
  }
}

// QKV projections fused via blockIdx.z. z==2 (V) writes transposed VT[n][m].
__global__ __launch_bounds__(256) void gemm_qkv(
    const __bf16* __restrict__ Xq, const __bf16* __restrict__ Xk, const __bf16* __restrict__ Xv,
    const __bf16* __restrict__ Wqb, const __bf16* __restrict__ Wkb, const __bf16* __restrict__ Wvb,
    const float* __restrict__ bq, const float* __restrict__ bk, const float* __restrict__ bv,
    __bf16* __restrict__ Qo, __bf16* __restrict__ Ko, __bf16* __restrict__ VTo)
{
  __shared__ __bf16 A_lds[128 * 64];
  __shared__ __bf16 B_lds[128 * 64];
  const int z = blockIdx.z;
  const __bf16* A = (z == 0) ? Xq : (z == 1) ? Xk : Xv;
  const __bf16* W = (z == 0) ? Wqb : (z == 1) ? Wkb : Wvb;
  const float* bias = (z == 0) ? bq : (z == 1) ? bk : bv;
  const int m0 = blockIdx.y * 128, n0 = blockIdx.x * 128;

  f32x4 acc[4][4];
  const f32x4 z4 = {0.f, 0.f, 0.f, 0.f};
  #pragma unroll
  for (int i = 0; i < 4; ++i)
    #pragma unroll
    for (int j = 0; j < 4; ++j) acc[i][j] = z4;

  gemm_tile_128(A, W, m0, n0, A_lds, B_lds, acc);

  const int tid = threadIdx.x;
  const int l = tid & 63, l15 = l & 15, l4 = l >> 4;
  const int w = tid >> 6;
  const int wr = (w >> 1) * 64, wc = (w & 1) * 64;

  if (z < 2) {
    __bf16* C = (z == 0) ? Qo : Ko;
    #pragma unroll
    for (int j = 0; j < 4; ++j) {
      const int n = n0 + wc + j * 16 + l15;
      const float bn = bias[n];
      #pragma unroll
      for (int i = 0; i < 4; ++i) {
        const int mbase = m0 + wr + i * 16 + 4 * l4;
        #pragma unroll
        for (int r = 0; r < 4; ++r)
          C[(size_t)(mbase + r) * 1024 + n] = (__bf16)(acc[i][j][r] + bn);
      }
    }
  } else {
    #pragma unroll
    for (int j = 0; j < 4; ++j) {
      const int n = n0 + wc + j * 16 + l15;
      const float bn = bias[n];
      #pragma unroll
      for (int i = 0; i < 4; ++i) {
        const int mbase = m0 + wr + i * 16 + 4 * l4;   // multiple of 4 -> 8B aligned store
        bf16x4 v;
        #pragma unroll
        for (int r = 0; r < 4; ++r) v[r] = (__bf16)(acc[i][j][r] + bn);
        *(bf16x4*)(VTo + (size_t)n * 4096 + mbase) = v;
      }
    }
  }
}

// Output projection: fp32 out = CTX(bf16) @ Wo^T + bo
__global__ __launch_bounds__(256) void gemm_out_k(
    const __bf16* __restrict__ CTXb, const __bf16* __restrict__ Wob,
    const float* __restrict__ bo, float* __restrict__ out)
{
  __shared__ __bf16 A_lds[128 * 64];
  __shared__ __bf16 B_lds[128 * 64];
  const int m0 = blockIdx.y * 128, n0 = blockIdx.x * 128;

  f32x4 acc[4][4];
  const f32x4 z4 = {0.f, 0.f, 0.f, 0.f};
  #pragma unroll
  for (int i = 0; i < 4; ++i)
    #pragma unroll
    for (int j = 0; j < 4; ++j) acc[i][j] = z4;

  gemm_tile_128(CTXb, Wob, m0, n0, A_lds, B_lds, acc);

  const int tid = threadIdx.x;
  const int l = tid & 63, l15 = l & 15, l4 = l >> 4;
  const int w = tid >> 6;
  const int wr = (w >> 1) * 64, wc = (w & 1) * 64;

  #pragma unroll
  for (int j = 0; j < 4; ++j) {
    const int n = n0 + wc + j * 16 + l15;
    const float bn = bo[n];
    #pragma unroll
    for (int i = 0; i < 4; ++i) {
      const int mbase = m0 + wr + i * 16 + 4 * l4;
      #pragma unroll
      for (int r = 0; r < 4; ++r)
        out[(size_t)(mbase + r) * 1024 + n] = acc[i][j][r] + bn;
    }
  }
}

// ---------------- Flash attention: 16 q/wave, 1 wave per 64-thread block ----------------
// Grid 4096: bid = qw*32 + pair; qw in 0..127, q0 = qw*16 (covers 0..2047 per (b,h)).
// pair in low 5 bits -> bid%8 = pair%8 -> XCD affinity; 4 pairs/XCD, 2MB K+V per XCD L2.
// Q[4096][1024], K[4096][1024], VT[1024][4096] (row d = h*64+d, col = b*2048+s).
// Per kv-tile (KVBLK=64):
//   S^T = mfma(K, Q): sacc[kf], q = lane&15 (lane-local q-row), k = kf*16 + 4*(lane>>4) + r
//   softmax in-lane (15 fmax) + shfl_xor(16,32) across the 4-lane k-group
//   P packed bf16x4 -> Pl[16][80] (b64 writes); compiler barrier; read back bf16x8
//   ctx^T += mfma(V^T, P^T): col = q = lane&15 -> rescale is a per-lane scalar
__global__ __launch_bounds__(64, 4) void attn_kernel(
    const __bf16* __restrict__ Q, const __bf16* __restrict__ K,
    const __bf16* __restrict__ VT, __bf16* __restrict__ CTX)
{
  __shared__ __bf16 Pl[16][80];   // 2.5 KB, block == one wave

  const int tid = threadIdx.x;
  const int l = tid & 63, l15 = l & 15, l4 = l >> 4;
  const int bid = blockIdx.x;
  const int qw = bid >> 5, pair = bid & 31, h = pair & 15, b = pair >> 4;
  const int q0 = qw * 16;   // wave's first q-row within this (b,h); qw in 0..127

  // Q fragments in registers (wave's 16 q-rows x 64 d), used as the MFMA B-operand.
  const __bf16* Qbase = Q + (size_t)(b * 2048 + q0) * 1024 + h * 64;
  bf16x8 qa[2];
  #pragma unroll
  for (int df = 0; df < 2; ++df)
    qa[df] = *(const bf16x8*)(Qbase + (size_t)l15 * 1024 + df * 32 + l4 * 8);

  f32x4 ctxa[4];
  const f32x4 z4 = {0.f, 0.f, 0.f, 0.f};
  #pragma unroll
  for (int nf = 0; nf < 4; ++nf) ctxa[nf] = z4;

  float m_ = -INFINITY;
  float l_ = 0.f;

  const __bf16* Kbase = K + (size_t)b * 2048 * 1024 + h * 64;
  const __bf16* VTbase = VT + (size_t)(h * 64) * 4096 + (size_t)b * 2048;

  // preload K fragments for tile 0: kb[df][kf] = K[kf*16+l15][df*32+8*l4..]
  bf16x8 kb[2][4];
  #pragma unroll
  for (int df = 0; df < 2; ++df)
    #pragma unroll
    for (int kf = 0; kf < 4; ++kf)
      kb[df][kf] = *(const bf16x8*)(Kbase + (size_t)(kf * 16 + l15) * 1024 + df * 32 + l4 * 8);

  #pragma unroll 1
  for (int kv = 0; kv < 32; ++kv) {
    // ---- S^T = K . Q^T  (sacc[kf]: col=q=l15, row=k=kf*16+4*l4+r) ----
    f32x4 sacc[4];
    #pragma unroll
    for (int kf = 0; kf < 4; ++kf) sacc[kf] = z4;
    #pragma unroll
    for (int df = 0; df < 2; ++df)
      #pragma unroll
      for (int kf = 0; kf < 4; ++kf)
        sacc[kf] = mfma16(kb[df][kf], qa[df], sacc[kf]);

    // ---- issue V loads for this tile (consumed in PV, latency hidden by softmax) ----
    bf16x8 va[4][2];  // [nf][ks]: A-frag of V^T: row d=nf*16+l15, k=ks*32+8*l4..
    #pragma unroll
    for (int nf = 0; nf < 4; ++nf)
      #pragma unroll
      for (int ks = 0; ks < 2; ++ks)
        va[nf][ks] = *(const bf16x8*)(VTbase + (size_t)(nf * 16 + l15) * 4096 +
                                      kv * 64 + ks * 32 + l4 * 8);

    // ---- issue K loads for next tile (wrap harmlessly) ----
    {
      const int kvn = (kv + 1) & 31;
      #pragma unroll
      for (int df = 0; df < 2; ++df)
        #pragma unroll
        for (int kf = 0; kf < 4; ++kf)
          kb[df][kf] = *(const bf16x8*)(Kbase + (size_t)(kvn * 64 + kf * 16 + l15) * 1024 +
                                        df * 32 + l4 * 8);
    }

    // ---- online softmax, fully lane-local per q-row ----
    {
      float mx = sacc[0][0];
      #pragma unroll
      for (int kf = 0; kf < 4; ++kf)
        #pragma unroll
        for (int r = 0; r < 4; ++r) mx = fmaxf(mx, sacc[kf][r]);
      mx = fmaxf(mx, __shfl_xor(mx, 16));
      mx = fmaxf(mx, __shfl_xor(mx, 32));
      const float mn = fmaxf(m_, mx);
      const float scale = exp2f((m_ - mn) * SM_C);
      m_ = mn;
      const float nmC = -mn * SM_C;
      float ps = 0.f;
      #pragma unroll
      for (int kf = 0; kf < 4; ++kf) {
        bf16x4 pw;
        #pragma unroll
        for (int r = 0; r < 4; ++r) {
          const float p = exp2f(__builtin_fmaf(sacc[kf][r], SM_C, nmC));
          ps += p;
          pw[r] = (__bf16)p;
        }
        *(bf16x4*)&Pl[l15][kf * 16 + 4 * l4] = pw;  // b64
      }
      ps += __shfl_xor(ps, 16);
      ps += __shfl_xor(ps, 32);
      l_ = l_ * scale + ps;
      #pragma unroll
      for (int nf = 0; nf < 4; ++nf)
        #pragma unroll
        for (int r = 0; r < 4; ++r) ctxa[nf][r] *= scale;  // per-lane scalar rescale
    }

    // ---- compiler barrier: forbid reordering the bf16x8 reads above the bf16x4 writes ----
    asm volatile("" ::: "memory");

    // ---- ctx^T += V^T . P^T  (single wave: LDS pipe is in-order; lgkmcnt handled) ----
    bf16x8 pb[2];  // [ks]: B-frag: col q=l15, k=ks*32+8*l4..
    #pragma unroll
    for (int ks = 0; ks < 2; ++ks)
      pb[ks] = *(const bf16x8*)&Pl[l15][ks * 32 + 8 * l4];
    #pragma unroll
    for (int ks = 0; ks < 2; ++ks)
      #pragma unroll
      for (int nf = 0; nf < 4; ++nf)
        ctxa[nf] = mfma16(va[nf][ks], pb[ks], ctxa[nf]);
  }

  // ---- epilogue: ctx^T lane holds col q=l15, rows d=nf*16+4*l4+r ----
  __bf16* Cb = CTX + (size_t)(b * 2048 + q0) * 1024 + h * 64;
  const float inv = 1.0f / l_;
  #pragma unroll
  for (int nf = 0; nf < 4; ++nf) {
    bf16x4 o;
    #pragma unroll
    for (int r = 0; r < 4; ++r) o[r] = (__bf16)(ctxa[nf][r] * inv);
    *(bf16x4*)(Cb + (size_t)l15 * 1024 + nf * 16 + 4 * l4) = o;
  }
}

// ---------------- launch ----------------
extern "C" void kernel_launch(void* const* d_in, const int* in_sizes, int n_in,
                              void* d_out, int out_size, void* d_ws, size_t ws_size,
                              hipStream_t stream) {
  (void)in_sizes; (void)n_in; (void)out_size; (void)ws_size;
  const float* query = (const float*)d_in[0];
  const float* key_  = (const float*)d_in[1];
  const float* value = (const float*)d_in[2];
  const float* Wq = (const float*)d_in[3];
  const float* bq = (const float*)d_in[4];
  const float* Wk = (const float*)d_in[5];
  const float* bk = (const float*)d_in[6];
  const float* Wv = (const float*)d_in[7];
  const float* bv = (const float*)d_in[8];
  const float* Wo = (const float*)d_in[9];
  const float* bo = (const float*)d_in[10];
  float* out = (float*)d_out;

  char* ws = (char*)d_ws;
  const size_t MB = 1ull << 20;
  __bf16* Xq  = (__bf16*)(ws + 0 * MB);
  __bf16* Xk  = (__bf16*)(ws + 8 * MB);
  __bf16* Xv  = (__bf16*)(ws + 16 * MB);
  __bf16* Wqb = (__bf16*)(ws + 24 * MB);
  __bf16* Wkb = (__bf16*)(ws + 26 * MB);
  __bf16* Wvb = (__bf16*)(ws + 28 * MB);
  __bf16* Wob = (__bf16*)(ws + 30 * MB);
  __bf16* Qb  = (__bf16*)(ws + 32 * MB);
  __bf16* Kb  = (__bf16*)(ws + 40 * MB);
  __bf16* VTb = (__bf16*)(ws + 48 * MB);
  __bf16* CTXb= (__bf16*)(ws + 56 * MB);

  CvtArgs ca;
  ca.src[0] = query; ca.dst[0] = Xq;  ca.n8[0] = 4096 * 1024 / 8;
  ca.src[1] = key_;  ca.dst[1] = Xk;  ca.n8[1] = 4096 * 1024 / 8;
  ca.src[2] = value; ca.dst[2] = Xv;  ca.n8[2] = 4096 * 1024 / 8;
  ca.src[3] = Wq;    ca.dst[3] = Wqb; ca.n8[3] = 1024 * 1024 / 8;
  ca.src[4] = Wk;    ca.dst[4] = Wkb; ca.n8[4] = 1024 * 1024 / 8;
  ca.src[5] = Wv;    ca.dst[5] = Wvb; ca.n8[5] = 1024 * 1024 / 8;
  ca.src[6] = Wo;    ca.dst[6] = Wob; ca.n8[6] = 1024 * 1024 / 8;
  cvt_kernel<<<dim3(1024, 7), dim3(256), 0, stream>>>(ca);

  gemm_qkv<<<dim3(8, 32, 3), dim3(256), 0, stream>>>(
      Xq, Xk, Xv, Wqb, Wkb, Wvb, bq, bk, bv, Qb, Kb, VTb);

  attn_kernel<<<dim3(4096), dim3(64), 0, stream>>>(Qb, Kb, VTb, CTXb);

  gemm_out_k<<<dim3(8, 32), dim3(256), 0, stream>>>(CTXb, Wob, bo, out);
}

// Round 6
// 170.446 us; speedup vs baseline: 1.9049x; 1.9049x over previous
//
// R6: attn with block-shared double-buffered LDS K/V staging (reg-staged, padded),
//     R2's verified 32q/wave MFMA/softmax numerics, 2 barriers/tile.
//     L2 traffic 1.05GB -> 262MB. GEMMs/cvt bit-identical to R2 (known good).
#include <hip/hip_runtime.h>
#include <cstdint>
#include <cmath>

typedef __attribute__((ext_vector_type(8))) __bf16 bf16x8;
typedef __attribute__((ext_vector_type(4))) __bf16 bf16x4;
typedef __attribute__((ext_vector_type(4))) float f32x4;

static constexpr float SM_C = 0.125f * 1.44269504088896340736f; // 1/sqrt(64) * log2(e)

__device__ __forceinline__ f32x4 mfma16(bf16x8 a, bf16x8 b, f32x4 c) {
  return __builtin_amdgcn_mfma_f32_16x16x32_bf16(a, b, c, 0, 0, 0);
}

typedef __attribute__((address_space(1))) const void GVoid;
typedef __attribute__((address_space(3))) void LVoid;

__device__ __forceinline__ void load_lds16(const __bf16* g, __bf16* lds) {
  __builtin_amdgcn_global_load_lds((GVoid*)g, (LVoid*)lds, 16, 0, 0);
}

// ---------------- fp32 -> bf16 conversion (7 tensors in one launch) ----------------
struct CvtArgs {
  const float* src[7];
  __bf16* dst[7];
  int n8[7];
};

__global__ __launch_bounds__(256) void cvt_kernel(CvtArgs args) {
  const int t = blockIdx.y;
  const float* s = args.src[t];
  __bf16* d = args.dst[t];
  const int n8 = args.n8[t];
  for (int i = blockIdx.x * 256 + threadIdx.x; i < n8; i += gridDim.x * 256) {
    float4 f0 = reinterpret_cast<const float4*>(s)[2 * i];
    float4 f1 = reinterpret_cast<const float4*>(s)[2 * i + 1];
    bf16x8 o;
    o[0] = (__bf16)f0.x; o[1] = (__bf16)f0.y; o[2] = (__bf16)f0.z; o[3] = (__bf16)f0.w;
    o[4] = (__bf16)f1.x; o[5] = (__bf16)f1.y; o[6] = (__bf16)f1.z; o[7] = (__bf16)f1.w;
    reinterpret_cast<bf16x8*>(d)[i] = o;
  }
}

// ---------------- GEMM core (m97 config): 128x128 tile, BK=64, global_load_lds w16 ----------------
__device__ __forceinline__ void gemm_tile_128(
    const __bf16* __restrict__ A, const __bf16* __restrict__ W,
    int m0, int n0, __bf16* A_lds, __bf16* B_lds, f32x4 acc[4][4])
{
  const int tid = threadIdx.x;
  const int l = tid & 63, l15 = l & 15, l4 = l >> 4;
  const int w = tid >> 6;
  const int wr = (w >> 1) * 64, wc = (w & 1) * 64;

  #pragma unroll 1
  for (int kt = 0; kt < 1024; kt += 64) {
    __syncthreads();  // previous compute done before restaging
    #pragma unroll
    for (int c = 0; c < 4; ++c) {
      const int u = c * 256 + tid;          // 0..1023 16B units
      const int row = u >> 3, ch = (u & 7) * 8;
      load_lds16(A + (size_t)(m0 + row) * 1024 + kt + ch, A_lds + u * 8);
      load_lds16(W + (size_t)(n0 + row) * 1024 + kt + ch, B_lds + u * 8);
    }
    __syncthreads();  // drains vmcnt: LDS staged
    #pragma unroll
    for (int ks = 0; ks < 2; ++ks) {
      bf16x8 af[4], bw[4];
      #pragma unroll
      for (int i = 0; i < 4; ++i) {
        af[i] = *(const bf16x8*)(A_lds + (size_t)(wr + i * 16 + l15) * 64 + ks * 32 + l4 * 8);
        bw[i] = *(const bf16x8*)(B_lds + (size_t)(wc + i * 16 + l15) * 64 + ks * 32 + l4 * 8);
      }
      #pragma unroll
      for (int i = 0; i < 4; ++i)
        #pragma unroll
        for (int j = 0; j < 4; ++j)
          acc[i][j] = mfma16(af[i], bw[j], acc[i][j]);
    }
  }
}

// QKV projections fused via blockIdx.z. z==2 (V) writes transposed VT[n][m].
__global__ __launch_bounds__(256) void gemm_qkv(
    const __bf16* __restrict__ Xq, const __bf16* __restrict__ Xk, const __bf16* __restrict__ Xv,
    const __bf16* __restrict__ Wqb, const __bf16* __restrict__ Wkb, const __bf16* __restrict__ Wvb,
    const float* __restrict__ bq, const float* __restrict__ bk, const float* __restrict__ bv,
    __bf16* __restrict__ Qo, __bf16* __restrict__ Ko, __bf16* __restrict__ VTo)
{
  __shared__ __bf16 A_lds[128 * 64];
  __shared__ __bf16 B_lds[128 * 64];
  const int z = blockIdx.z;
  const __bf16* A = (z == 0) ? Xq : (z == 1) ? Xk : Xv;
  const __bf16* W = (z == 0) ? Wqb : (z == 1) ? Wkb : Wvb;
  const float* bias = (z == 0) ? bq : (z == 1) ? bk : bv;
  const int m0 = blockIdx.y * 128, n0 = blockIdx.x * 128;

  f32x4 acc[4][4];
  const f32x4 z4 = {0.f, 0.f, 0.f, 0.f};
  #pragma unroll
  for (int i = 0; i < 4; ++i)
    #pragma unroll
    for (int j = 0; j < 4; ++j) acc[i][j] = z4;

  gemm_tile_128(A, W, m0, n0, A_lds, B_lds, acc);

  const int tid = threadIdx.x;
  const int l = tid & 63, l15 = l & 15, l4 = l >> 4;
  const int w = tid >> 6;
  const int wr = (w >> 1) * 64, wc = (w & 1) * 64;

  if (z < 2) {
    __bf16* C = (z == 0) ? Qo : Ko;
    #pragma unroll
    for (int j = 0; j < 4; ++j) {
      const int n = n0 + wc + j * 16 + l15;
      const float bn = bias[n];
      #pragma unroll
      for (int i = 0; i < 4; ++i) {
        const int mbase = m0 + wr + i * 16 + 4 * l4;
        #pragma unroll
        for (int r = 0; r < 4; ++r)
          C[(size_t)(mbase + r) * 1024 + n] = (__bf16)(acc[i][j][r] + bn);
      }
    }
  } else {
    #pragma unroll
    for (int j = 0; j < 4; ++j) {
      const int n = n0 + wc + j * 16 + l15;
      const float bn = bias[n];
      #pragma unroll
      for (int i = 0; i < 4; ++i) {
        const int mbase = m0 + wr + i * 16 + 4 * l4;   // multiple of 4 -> 8B aligned store
        bf16x4 v;
        #pragma unroll
        for (int r = 0; r < 4; ++r) v[r] = (__bf16)(acc[i][j][r] + bn);
        *(bf16x4*)(VTo + (size_t)n * 4096 + mbase) = v;
      }
    }
  }
}

// Output projection: fp32 out = CTX(bf16) @ Wo^T + bo
__global__ __launch_bounds__(256) void gemm_out_k(
    const __bf16* __restrict__ CTXb, const __bf16* __restrict__ Wob,
    const float* __restrict__ bo, float* __restrict__ out)
{
  __shared__ __bf16 A_lds[128 * 64];
  __shared__ __bf16 B_lds[128 * 64];
  const int m0 = blockIdx.y * 128, n0 = blockIdx.x * 128;

  f32x4 acc[4][4];
  const f32x4 z4 = {0.f, 0.f, 0.f, 0.f};
  #pragma unroll
  for (int i = 0; i < 4; ++i)
    #pragma unroll
    for (int j = 0; j < 4; ++j) acc[i][j] = z4;

  gemm_tile_128(CTXb, Wob, m0, n0, A_lds, B_lds, acc);

  const int tid = threadIdx.x;
  const int l = tid & 63, l15 = l & 15, l4 = l >> 4;
  const int w = tid >> 6;
  const int wr = (w >> 1) * 64, wc = (w & 1) * 64;

  #pragma unroll
  for (int j = 0; j < 4; ++j) {
    const int n = n0 + wc + j * 16 + l15;
    const float bn = bo[n];
    #pragma unroll
    for (int i = 0; i < 4; ++i) {
      const int mbase = m0 + wr + i * 16 + 4 * l4;
      #pragma unroll
      for (int r = 0; r < 4; ++r)
        out[(size_t)(mbase + r) * 1024 + n] = acc[i][j][r] + bn;
    }
  }
}

// ---------------- Flash attention: block-shared dbuf LDS K/V, 4 waves x 32 q ----------------
// Grid 512: bid = qt*32 + pair (pair%8 -> XCD; per-XCD 4 pairs x 512KB K/V = 2MB L2-resident).
// Block 256 thr = 4 waves; block covers 128 q-rows (wave w: q0 = qt*128 + w*32).
// Per kv-tile (KVBLK=64), double-buffered:
//   stage: 256 threads reg-stage K[64][64] and VT[64][64] into padded LDS [64][72]
//          (loads for tile t+1 issued right after the stage barrier -> full-tile latency cover)
//   S^T = mfma(K_lds, Q): col=q=lane&15 (lane-local q-row), k = kf*16 + 4*(lane>>4) + r
//   softmax in-lane (15 fmax) + shfl_xor(16,32)
//   P -> wave-private Pl[32][80] (b64 writes), read b128
//   ctx^T += mfma(VT_lds, P^T): col=q -> rescale is a per-lane scalar
__global__ __launch_bounds__(256, 2) void attn_kernel(
    const __bf16* __restrict__ Q, const __bf16* __restrict__ K,
    const __bf16* __restrict__ VT, __bf16* __restrict__ CTX)
{
  __shared__ __bf16 Kl[2][64][72];   // 18 KB
  __shared__ __bf16 Vl[2][64][72];   // 18 KB ([d][s] tile of VT)
  __shared__ __bf16 Pl[4][32][80];   // 20.5 KB, wave-private slabs

  const int tid = threadIdx.x;
  const int w = tid >> 6, l = tid & 63, l15 = l & 15, l4 = l >> 4;
  const int bid = blockIdx.x;
  const int qt = bid >> 5, pair = bid & 31, h = pair & 15, b = pair >> 4;
  const int q0 = qt * 128 + w * 32;

  // staging coordinates: this thread covers 16B chunks u = tid and u = tid+256 (of 512)
  const int sr0 = tid >> 3, sc0 = (tid & 7) * 8;          // chunk 0: row, col(elem)
  const int sr1 = (tid + 256) >> 3, sc1 = (tid & 7) * 8;  // chunk 1 (row += 32)

  const __bf16* Kbase = K + (size_t)b * 2048 * 1024 + h * 64;
  const __bf16* VTbase = VT + (size_t)(h * 64) * 4096 + (size_t)b * 2048;

  // Q fragments in registers (wave's 32 q-rows x 64 d), used as the MFMA B-operand.
  const __bf16* Qbase = Q + (size_t)(b * 2048 + q0) * 1024 + h * 64;
  bf16x8 qa[2][2];
  #pragma unroll
  for (int qf = 0; qf < 2; ++qf)
    #pragma unroll
    for (int df = 0; df < 2; ++df)
      qa[qf][df] = *(const bf16x8*)(Qbase + (size_t)(qf * 16 + l15) * 1024 + df * 32 + l4 * 8);

  f32x4 ctxa[2][4];
  const f32x4 z4 = {0.f, 0.f, 0.f, 0.f};
  #pragma unroll
  for (int qf = 0; qf < 2; ++qf)
    #pragma unroll
    for (int nf = 0; nf < 4; ++nf) ctxa[qf][nf] = z4;

  float m_[2] = {-INFINITY, -INFINITY};
  float l_[2] = {0.f, 0.f};

  // prologue: issue tile 0 staging loads into registers
  bf16x8 kst0, kst1, vst0, vst1;
  kst0 = *(const bf16x8*)(Kbase + (size_t)sr0 * 1024 + sc0);
  kst1 = *(const bf16x8*)(Kbase + (size_t)sr1 * 1024 + sc1);
  vst0 = *(const bf16x8*)(VTbase + (size_t)sr0 * 4096 + sc0);
  vst1 = *(const bf16x8*)(VTbase + (size_t)sr1 * 4096 + sc1);

  #pragma unroll 1
  for (int kv = 0; kv < 32; ++kv) {
    const int buf = kv & 1;
    // ---- write staged regs to LDS (vmcnt auto-inserted), publish ----
    *(bf16x8*)&Kl[buf][sr0][sc0] = kst0;
    *(bf16x8*)&Kl[buf][sr1][sc1] = kst1;
    *(bf16x8*)&Vl[buf][sr0][sc0] = vst0;
    *(bf16x8*)&Vl[buf][sr1][sc1] = vst1;
    __syncthreads();

    // ---- issue staging loads for tile kv+1 (in flight across the whole compute) ----
    if (kv < 31) {
      const int s = (kv + 1) * 64;
      kst0 = *(const bf16x8*)(Kbase + (size_t)(s + sr0) * 1024 + sc0);
      kst1 = *(const bf16x8*)(Kbase + (size_t)(s + sr1) * 1024 + sc1);
      vst0 = *(const bf16x8*)(VTbase + (size_t)sr0 * 4096 + s + sc0);
      vst1 = *(const bf16x8*)(VTbase + (size_t)sr1 * 4096 + s + sc1);
    }

    // ---- S^T = K . Q^T  (sacc[qf][kf]: col=q=l15, row=k=kf*16+4*l4+r) ----
    bf16x8 kb[2][4];
    #pragma unroll
    for (int df = 0; df < 2; ++df)
      #pragma unroll
      for (int kf = 0; kf < 4; ++kf)
        kb[df][kf] = *(const bf16x8*)&Kl[buf][kf * 16 + l15][df * 32 + l4 * 8];
    f32x4 sacc[2][4];
    #pragma unroll
    for (int qf = 0; qf < 2; ++qf)
      #pragma unroll
      for (int kf = 0; kf < 4; ++kf) sacc[qf][kf] = z4;
    #pragma unroll
    for (int df = 0; df < 2; ++df)
      #pragma unroll
      for (int qf = 0; qf < 2; ++qf)
        #pragma unroll
        for (int kf = 0; kf < 4; ++kf)
          sacc[qf][kf] = mfma16(kb[df][kf], qa[qf][df], sacc[qf][kf]);

    // ---- V fragments from LDS (independent of softmax; scheduler hoists) ----
    bf16x8 va[4][2];  // [nf][ks]: A-frag of V^T: row d=nf*16+l15, k=ks*32+8*l4..
    #pragma unroll
    for (int nf = 0; nf < 4; ++nf)
      #pragma unroll
      for (int ks = 0; ks < 2; ++ks)
        va[nf][ks] = *(const bf16x8*)&Vl[buf][nf * 16 + l15][ks * 32 + l4 * 8];

    // ---- online softmax, fully lane-local per q-row ----
    #pragma unroll
    for (int qf = 0; qf < 2; ++qf) {
      float mx = sacc[qf][0][0];
      #pragma unroll
      for (int kf = 0; kf < 4; ++kf)
        #pragma unroll
        for (int r = 0; r < 4; ++r) mx = fmaxf(mx, sacc[qf][kf][r]);
      mx = fmaxf(mx, __shfl_xor(mx, 16));
      mx = fmaxf(mx, __shfl_xor(mx, 32));
      const float mn = fmaxf(m_[qf], mx);
      const float scale = exp2f((m_[qf] - mn) * SM_C);
      m_[qf] = mn;
      const float nmC = -mn * SM_C;
      float ps = 0.f;
      #pragma unroll
      for (int kf = 0; kf < 4; ++kf) {
        bf16x4 pw;
        #pragma unroll
        for (int r = 0; r < 4; ++r) {
          const float p = exp2f(__builtin_fmaf(sacc[qf][kf][r], SM_C, nmC));
          ps += p;
          pw[r] = (__bf16)p;
        }
        *(bf16x4*)&Pl[w][qf * 16 + l15][kf * 16 + 4 * l4] = pw;  // b64
      }
      ps += __shfl_xor(ps, 16);
      ps += __shfl_xor(ps, 32);
      l_[qf] = l_[qf] * scale + ps;
      #pragma unroll
      for (int nf = 0; nf < 4; ++nf)
        #pragma unroll
        for (int r = 0; r < 4; ++r) ctxa[qf][nf][r] *= scale;  // per-lane scalar rescale
    }

    // ---- compiler barrier: forbid reordering the bf16x8 Pl reads above the bf16x4 writes ----
    asm volatile("" ::: "memory");

    // ---- ctx^T += V^T . P^T  (Pl wave-private; in-wave lgkmcnt ordering) ----
    bf16x8 pb[2][2];  // [qf][ks]: B-frag: col q=l15, k=ks*32+8*l4..
    #pragma unroll
    for (int qf = 0; qf < 2; ++qf)
      #pragma unroll
      for (int ks = 0; ks < 2; ++ks)
        pb[qf][ks] = *(const bf16x8*)&Pl[w][qf * 16 + l15][ks * 32 + 8 * l4];
    #pragma unroll
    for (int ks = 0; ks < 2; ++ks)
      #pragma unroll
      for (int qf = 0; qf < 2; ++qf)
        #pragma unroll
        for (int nf = 0; nf < 4; ++nf)
          ctxa[qf][nf] = mfma16(va[nf][ks], pb[qf][ks], ctxa[qf][nf]);

    __syncthreads();  // all waves done reading buf before it is overwritten
  }

  // ---- epilogue: ctx^T lane holds col q=l15, rows d=nf*16+4*l4+r ----
  __bf16* Cb = CTX + (size_t)(b * 2048 + q0) * 1024 + h * 64;
  #pragma unroll
  for (int qf = 0; qf < 2; ++qf) {
    const float inv = 1.0f / l_[qf];
    #pragma unroll
    for (int nf = 0; nf < 4; ++nf) {
      bf16x4 o;
      #pragma unroll
      for (int r = 0; r < 4; ++r) o[r] = (__bf16)(ctxa[qf][nf][r] * inv);
      *(bf16x4*)(Cb + (size_t)(qf * 16 + l15) * 1024 + nf * 16 + 4 * l4) = o;
    }
  }
}

// ---------------- launch ----------------
extern "C" void kernel_launch(void* const* d_in, const int* in_sizes, int n_in,
                              void* d_out, int out_size, void* d_ws, size_t ws_size,
                              hipStream_t stream) {
  (void)in_sizes; (void)n_in; (void)out_size; (void)ws_size;
  const float* query = (const float*)d_in[0];
  const float* key_  = (const float*)d_in[1];
  const float* value = (const float*)d_in[2];
  const float* Wq = (const float*)d_in[3];
  const float* bq = (const float*)d_in[4];
  const float* Wk = (const float*)d_in[5];
  const float* bk = (const float*)d_in[6];
  const float* Wv = (const float*)d_in[7];
  const float* bv = (const float*)d_in[8];
  const float* Wo = (const float*)d_in[9];
  const float* bo = (const float*)d_in[10];
  float* out = (float*)d_out;

  char* ws = (char*)d_ws;
  const size_t MB = 1ull << 20;
  __bf16* Xq  = (__bf16*)(ws + 0 * MB);
  __bf16* Xk  = (__bf16*)(ws + 8 * MB);
  __bf16* Xv  = (__bf16*)(ws + 16 * MB);
  __bf16* Wqb = (__bf16*)(ws + 24 * MB);
  __bf16* Wkb = (__bf16*)(ws + 26 * MB);
  __bf16* Wvb = (__bf16*)(ws + 28 * MB);
  __bf16* Wob = (__bf16*)(ws + 30 * MB);
  __bf16* Qb  = (__bf16*)(ws + 32 * MB);
  __bf16* Kb  = (__bf16*)(ws + 40 * MB);
  __bf16* VTb = (__bf16*)(ws + 48 * MB);
  __bf16* CTXb= (__bf16*)(ws + 56 * MB);

  CvtArgs ca;
  ca.src[0] = query; ca.dst[0] = Xq;  ca.n8[0] = 4096 * 1024 / 8;
  ca.src[1] = key_;  ca.dst[1] = Xk;  ca.n8[1] = 4096 * 1024 / 8;
  ca.src[2] = value; ca.dst[2] = Xv;  ca.n8[2] = 4096 * 1024 / 8;
  ca.src[3] = Wq;    ca.dst[3] = Wqb; ca.n8[3] = 1024 * 1024 / 8;
  ca.src[4] = Wk;    ca.dst[4] = Wkb; ca.n8[4] = 1024 * 1024 / 8;
  ca.src[5] = Wv;    ca.dst[5] = Wvb; ca.n8[5] = 1024 * 1024 / 8;
  ca.src[6] = Wo;    ca.dst[6] = Wob; ca.n8[6] = 1024 * 1024 / 8;
  cvt_kernel<<<dim3(1024, 7), dim3(256), 0, stream>>>(ca);

  gemm_qkv<<<dim3(8, 32, 3), dim3(256), 0, stream>>>(
      Xq, Xk, Xv, Wqb, Wkb, Wvb, bq, bk, bv, Qb, Kb, VTb);

  attn_kernel<<<dim3(512), dim3(256), 0, stream>>>(Qb, Kb, VTb, CTXb);

  gemm_out_k<<<dim3(8, 32), dim3(256), 0, stream>>>(CTXb, Wob, bo, out);
}